// Round 4
// baseline (345.013 us; speedup 1.0000x reference)
//
#include <hip/hip_runtime.h>
#include <math.h>

#define H 2048

__device__ __forceinline__ float sigmoidf_(float v) {
    return 1.0f / (1.0f + expf(-v));
}

__device__ __forceinline__ float dot4(float4 a, float4 b) {
    return a.x * b.x + a.y * b.y + a.z * b.z + a.w * b.w;
}

// 4 interleaved butterfly chains, depth 6.
__device__ __forceinline__ void bfly4(float& a, float& b, float& c, float& d) {
#pragma unroll
    for (int off = 32; off > 0; off >>= 1) {
        a += __shfl_down(a, off, 64);
        b += __shfl_down(b, off, 64);
        c += __shfl_down(c, off, 64);
        d += __shfl_down(d, off, 64);
    }
}

// Layers 1,2 — split-K (4 waves = K-quarters), 1 element per block.
// grid 2048 = 8 blocks/CU, __launch_bounds__(256,8) keeps all 8 resident:
// 32 waves/CU (VGPR capped at 64 -> kernel sized to ~58).
// Load schedule is PINNED with sched_barrier(0): a 4-float4 gate batch is
// always in flight while the previous batch's FMAs run (compiler emits
// counted vmcnt(4) waits, never a full drain until the last gate).
__global__ __launch_bounds__(256, 8)
void lstm_layer(const float* __restrict__ Wih, const float* __restrict__ Whh,
                const float* __restrict__ bih, const float* __restrict__ bhh,
                const float* __restrict__ xin,  // [H] prev-layer h
                const float* __restrict__ hin,  // [H]
                const float* __restrict__ cin,  // [H]
                float* __restrict__ hout, float* __restrict__ cout)
{
    const int t    = blockIdx.x;          // 0..2047, uniform per block
    const int tid  = threadIdx.x;
    const int w    = tid >> 6;            // wave id = K-quarter
    const int lane = tid & 63;
    const int idx  = (w << 7) + lane;     // float4 index; row = 512 float4

    // uniform scalar loads (s_load path, lgkmcnt not vmcnt)
    const float b_i = bih[t]         + bhh[t];
    const float b_f = bih[H + t]     + bhh[H + t];
    const float b_g = bih[2 * H + t] + bhh[2 * H + t];
    const float b_o = bih[3 * H + t] + bhh[3 * H + t];
    const float cprev = cin[t];

    const float4* x4  = (const float4*)xin;
    const float4* h4  = (const float4*)hin;
    const float4* wi0 = (const float4*)(Wih + (size_t)t * H);
    const float4* wh0 = (const float4*)(Whh + (size_t)t * H);
    const float4* wi1 = (const float4*)(Wih + (size_t)(H + t) * H);
    const float4* wh1 = (const float4*)(Whh + (size_t)(H + t) * H);
    const float4* wi2 = (const float4*)(Wih + (size_t)(2 * H + t) * H);
    const float4* wh2 = (const float4*)(Whh + (size_t)(2 * H + t) * H);
    const float4* wi3 = (const float4*)(Wih + (size_t)(3 * H + t) * H);
    const float4* wh3 = (const float4*)(Whh + (size_t)(3 * H + t) * H);

    // Issue order matters: x/h first (consumed by every gate), then gate-i
    // batch A, then gate-f batch B. Consuming A waits vmcnt(4) with B in
    // flight. 2-buffer ping-pong, all names static (no scratch).
    const float4 xv0 = x4[idx], xv1 = x4[idx + 64];
    const float4 hv0 = h4[idx], hv1 = h4[idx + 64];
    float4 A0 = wi0[idx], A1 = wi0[idx + 64];
    float4 A2 = wh0[idx], A3 = wh0[idx + 64];
    float4 B0 = wi1[idx], B1 = wi1[idx + 64];
    float4 B2 = wh1[idx], B3 = wh1[idx + 64];
    __builtin_amdgcn_sched_barrier(0);

    float s_i = (dot4(A0, xv0) + dot4(A2, hv0)) + (dot4(A1, xv1) + dot4(A3, hv1));
    A0 = wi2[idx]; A1 = wi2[idx + 64];          // gate-g batch in flight
    A2 = wh2[idx]; A3 = wh2[idx + 64];
    __builtin_amdgcn_sched_barrier(0);

    float s_f = (dot4(B0, xv0) + dot4(B2, hv0)) + (dot4(B1, xv1) + dot4(B3, hv1));
    B0 = wi3[idx]; B1 = wi3[idx + 64];          // gate-o batch in flight
    B2 = wh3[idx]; B3 = wh3[idx + 64];
    __builtin_amdgcn_sched_barrier(0);

    float s_g = (dot4(A0, xv0) + dot4(A2, hv0)) + (dot4(A1, xv1) + dot4(A3, hv1));
    float s_o = (dot4(B0, xv0) + dot4(B2, hv0)) + (dot4(B1, xv1) + dot4(B3, hv1));

    bfly4(s_i, s_f, s_g, s_o);

    __shared__ float part[4][4];
    if (lane == 0) {
        part[w][0] = s_i; part[w][1] = s_f; part[w][2] = s_g; part[w][3] = s_o;
    }
    __syncthreads();
    if (tid == 0) {
        float gi = part[0][0] + part[1][0] + part[2][0] + part[3][0] + b_i;
        float gf = part[0][1] + part[1][1] + part[2][1] + part[3][1] + b_f;
        float gg = part[0][2] + part[1][2] + part[2][2] + part[3][2] + b_g;
        float go = part[0][3] + part[1][3] + part[2][3] + part[3][3] + b_o;
        float c2 = sigmoidf_(gf) * cprev + sigmoidf_(gi) * tanhf(gg);
        float h2 = sigmoidf_(go) * tanhf(c2);
        cout[t] = c2;
        hout[t] = h2;
    }
}

// Layer 0 — Wih0 is [4H,1]; x*Wih0 folded into the bias. Only 4 Whh rows:
// all 8 payload loads + 2 h-vector loads issued up front (10 float4 = 40
// VGPR), pinned, then consumed in issue order (descending vmcnt waits).
__global__ __launch_bounds__(256, 8)
void lstm_layer0(const float* __restrict__ Wih0,  // [4H]
                 const float* __restrict__ Whh,   // [4H,H]
                 const float* __restrict__ bih, const float* __restrict__ bhh,
                 const float* __restrict__ xs,    // [1]
                 const float* __restrict__ hin, const float* __restrict__ cin,
                 float* __restrict__ hout, float* __restrict__ cout)
{
    const int t    = blockIdx.x;
    const int tid  = threadIdx.x;
    const int w    = tid >> 6;
    const int lane = tid & 63;
    const int idx  = (w << 7) + lane;

    const float x = xs[0];
    const float b_i = bih[t]         + bhh[t]         + x * Wih0[t];
    const float b_f = bih[H + t]     + bhh[H + t]     + x * Wih0[H + t];
    const float b_g = bih[2 * H + t] + bhh[2 * H + t] + x * Wih0[2 * H + t];
    const float b_o = bih[3 * H + t] + bhh[3 * H + t] + x * Wih0[3 * H + t];
    const float cprev = cin[t];

    const float4* h4 = (const float4*)hin;
    const float4* wi = (const float4*)(Whh + (size_t)t * H);
    const float4* wf = (const float4*)(Whh + (size_t)(H + t) * H);
    const float4* wg = (const float4*)(Whh + (size_t)(2 * H + t) * H);
    const float4* wo = (const float4*)(Whh + (size_t)(3 * H + t) * H);

    const float4 hv0 = h4[idx], hv1 = h4[idx + 64];
    float4 a0 = wi[idx], a1 = wi[idx + 64];
    float4 b0 = wf[idx], b1 = wf[idx + 64];
    float4 c0 = wg[idx], c1 = wg[idx + 64];
    float4 d0 = wo[idx], d1 = wo[idx + 64];
    __builtin_amdgcn_sched_barrier(0);

    float s_i = dot4(a0, hv0) + dot4(a1, hv1);
    float s_f = dot4(b0, hv0) + dot4(b1, hv1);
    float s_g = dot4(c0, hv0) + dot4(c1, hv1);
    float s_o = dot4(d0, hv0) + dot4(d1, hv1);

    bfly4(s_i, s_f, s_g, s_o);

    __shared__ float part[4][4];
    if (lane == 0) {
        part[w][0] = s_i; part[w][1] = s_f; part[w][2] = s_g; part[w][3] = s_o;
    }
    __syncthreads();
    if (tid == 0) {
        float gi = part[0][0] + part[1][0] + part[2][0] + part[3][0] + b_i;
        float gf = part[0][1] + part[1][1] + part[2][1] + part[3][1] + b_f;
        float gg = part[0][2] + part[1][2] + part[2][2] + part[3][2] + b_g;
        float go = part[0][3] + part[1][3] + part[2][3] + part[3][3] + b_o;
        float c2 = sigmoidf_(gf) * cprev + sigmoidf_(gi) * tanhf(gg);
        float h2 = sigmoidf_(go) * tanhf(c2);
        cout[t] = c2;
        hout[t] = h2;
    }
}

// y = dot(Wout, h) + bout   (single block)
__global__ __launch_bounds__(256)
void out_proj(const float* __restrict__ Wout,
              const float* __restrict__ bout,
              const float* __restrict__ h,
              float* __restrict__ y)
{
    __shared__ float partl[4];
    const int tid = threadIdx.x;
    const float4* W4 = (const float4*)Wout;
    const float4* h4 = (const float4*)h;
    float acc = 0.0f;
#pragma unroll
    for (int k = 0; k < 2; ++k) {
        int i = tid + 256 * k;
        float4 a = W4[i];
        float4 b = h4[i];
        acc += a.x * b.x + a.y * b.y + a.z * b.z + a.w * b.w;
    }
#pragma unroll
    for (int off = 32; off > 0; off >>= 1) acc += __shfl_down(acc, off, 64);
    if ((tid & 63) == 0) partl[tid >> 6] = acc;
    __syncthreads();
    if (tid == 0) y[0] = partl[0] + partl[1] + partl[2] + partl[3] + bout[0];
}

extern "C" void kernel_launch(void* const* d_in, const int* in_sizes, int n_in,
                              void* d_out, int out_size, void* d_ws, size_t ws_size,
                              hipStream_t stream) {
    const float* x    = (const float*)d_in[0];
    const float* hin  = (const float*)d_in[1];   // [3,1,H]
    const float* cin  = (const float*)d_in[2];   // [3,1,H]
    const float* Wih0 = (const float*)d_in[3];
    const float* Whh0 = (const float*)d_in[4];
    const float* bih0 = (const float*)d_in[5];
    const float* bhh0 = (const float*)d_in[6];
    const float* Wih1 = (const float*)d_in[7];
    const float* Whh1 = (const float*)d_in[8];
    const float* bih1 = (const float*)d_in[9];
    const float* bhh1 = (const float*)d_in[10];
    const float* Wih2 = (const float*)d_in[11];
    const float* Whh2 = (const float*)d_in[12];
    const float* bih2 = (const float*)d_in[13];
    const float* bhh2 = (const float*)d_in[14];
    const float* Wout = (const float*)d_in[15];
    const float* bout = (const float*)d_in[16];

    float* out = (float*)d_out;
    float* y  = out;              // [1]
    float* hN = out + 1;          // [3,H]
    float* cN = out + 1 + 3 * H;  // [3,H]

    lstm_layer0<<<2048, 256, 0, stream>>>(Wih0, Whh0, bih0, bhh0, x,
                                          hin, cin, hN, cN);
    lstm_layer<<<2048, 256, 0, stream>>>(Wih1, Whh1, bih1, bhh1,
                                         hN, hin + H, cin + H,
                                         hN + H, cN + H);
    lstm_layer<<<2048, 256, 0, stream>>>(Wih2, Whh2, bih2, bhh2,
                                         hN + H, hin + 2 * H, cin + 2 * H,
                                         hN + 2 * H, cN + 2 * H);
    out_proj<<<1, 256, 0, stream>>>(Wout, bout, hN + 2 * H, y);
}

// Round 5
// 326.249 us; speedup vs baseline: 1.0575x; 1.0575x over previous
//
#include <hip/hip_runtime.h>
#include <math.h>

#define H 2048

__device__ __forceinline__ float sigmoidf_(float v) {
    return 1.0f / (1.0f + expf(-v));
}

__device__ __forceinline__ float dot4(float4 a, float4 b) {
    return a.x * b.x + a.y * b.y + a.z * b.z + a.w * b.w;
}

// 4 interleaved butterfly chains, depth 6.
__device__ __forceinline__ void bfly4(float& a, float& b, float& c, float& d) {
#pragma unroll
    for (int off = 32; off > 0; off >>= 1) {
        a += __shfl_down(a, off, 64);
        b += __shfl_down(b, off, 64);
        c += __shfl_down(c, off, 64);
        d += __shfl_down(d, off, 64);
    }
}

// Layers 1,2 — split-K (4 waves = K-quarters), 1 element per block, grid 2048.
// __launch_bounds__(256,4): 128-VGPR cap. ALL 20 wave-loads (x,h + 4 gates'
// weight batches = 80 payload VGPRs) are issued as one pinned cluster
// (sched_barrier stops sinking), then consumed in issue order -> compiler
// emits descending counted vmcnt(12/8/4/0); up to 20KB/wave in flight.
// Round-4 lesson: at (256,8) this payload spilled (VGPR=32, WRITE=51MB);
// the 128 cap fits it with headroom.
__global__ __launch_bounds__(256, 4)
void lstm_layer(const float* __restrict__ Wih, const float* __restrict__ Whh,
                const float* __restrict__ bih, const float* __restrict__ bhh,
                const float* __restrict__ xin,  // [H] prev-layer h
                const float* __restrict__ hin,  // [H]
                const float* __restrict__ cin,  // [H]
                float* __restrict__ hout, float* __restrict__ cout)
{
    const int t    = blockIdx.x;          // 0..2047, uniform per block
    const int tid  = threadIdx.x;
    const int w    = tid >> 6;            // wave id = K-quarter
    const int lane = tid & 63;
    const int idx  = (w << 7) + lane;     // float4 index; row = 512 float4

    // uniform scalar loads -> SGPR path
    const float b_i = bih[t]         + bhh[t];
    const float b_f = bih[H + t]     + bhh[H + t];
    const float b_g = bih[2 * H + t] + bhh[2 * H + t];
    const float b_o = bih[3 * H + t] + bhh[3 * H + t];
    const float cprev = cin[t];

    const float4* x4  = (const float4*)xin;
    const float4* h4  = (const float4*)hin;
    const float4* wi0 = (const float4*)(Wih + (size_t)t * H);
    const float4* wh0 = (const float4*)(Whh + (size_t)t * H);
    const float4* wi1 = (const float4*)(Wih + (size_t)(H + t) * H);
    const float4* wh1 = (const float4*)(Whh + (size_t)(H + t) * H);
    const float4* wi2 = (const float4*)(Wih + (size_t)(2 * H + t) * H);
    const float4* wh2 = (const float4*)(Whh + (size_t)(2 * H + t) * H);
    const float4* wi3 = (const float4*)(Wih + (size_t)(3 * H + t) * H);
    const float4* wh3 = (const float4*)(Whh + (size_t)(3 * H + t) * H);

    // ---- single pinned load cluster: 20 independent wave-loads ----
    const float4 xv0 = x4[idx], xv1 = x4[idx + 64];
    const float4 hv0 = h4[idx], hv1 = h4[idx + 64];
    float4 Ai0 = wi0[idx], Ai1 = wi0[idx + 64];
    float4 Ah0 = wh0[idx], Ah1 = wh0[idx + 64];
    float4 Bi0 = wi1[idx], Bi1 = wi1[idx + 64];
    float4 Bh0 = wh1[idx], Bh1 = wh1[idx + 64];
    float4 Ci0 = wi2[idx], Ci1 = wi2[idx + 64];
    float4 Ch0 = wh2[idx], Ch1 = wh2[idx + 64];
    float4 Di0 = wi3[idx], Di1 = wi3[idx + 64];
    float4 Dh0 = wh3[idx], Dh1 = wh3[idx + 64];
    __builtin_amdgcn_sched_barrier(0);

    // ---- consume in issue order: counted vmcnt, never a premature drain ----
    float s_i = (dot4(Ai0, xv0) + dot4(Ah0, hv0)) + (dot4(Ai1, xv1) + dot4(Ah1, hv1));
    float s_f = (dot4(Bi0, xv0) + dot4(Bh0, hv0)) + (dot4(Bi1, xv1) + dot4(Bh1, hv1));
    float s_g = (dot4(Ci0, xv0) + dot4(Ch0, hv0)) + (dot4(Ci1, xv1) + dot4(Ch1, hv1));
    float s_o = (dot4(Di0, xv0) + dot4(Dh0, hv0)) + (dot4(Di1, xv1) + dot4(Dh1, hv1));

    bfly4(s_i, s_f, s_g, s_o);

    __shared__ float part[4][4];
    if (lane == 0) {
        part[w][0] = s_i; part[w][1] = s_f; part[w][2] = s_g; part[w][3] = s_o;
    }
    __syncthreads();
    if (tid == 0) {
        float gi = part[0][0] + part[1][0] + part[2][0] + part[3][0] + b_i;
        float gf = part[0][1] + part[1][1] + part[2][1] + part[3][1] + b_f;
        float gg = part[0][2] + part[1][2] + part[2][2] + part[3][2] + b_g;
        float go = part[0][3] + part[1][3] + part[2][3] + part[3][3] + b_o;
        float c2 = sigmoidf_(gf) * cprev + sigmoidf_(gi) * tanhf(gg);
        float h2 = sigmoidf_(go) * tanhf(c2);
        cout[t] = c2;
        hout[t] = h2;
    }
}

// Layer 0 — Wih0 is [4H,1]; x*Wih0 folded into the bias. 10 wave-loads
// (40 payload VGPRs), same single pinned cluster. (256,4): no spill risk.
__global__ __launch_bounds__(256, 4)
void lstm_layer0(const float* __restrict__ Wih0,  // [4H]
                 const float* __restrict__ Whh,   // [4H,H]
                 const float* __restrict__ bih, const float* __restrict__ bhh,
                 const float* __restrict__ xs,    // [1]
                 const float* __restrict__ hin, const float* __restrict__ cin,
                 float* __restrict__ hout, float* __restrict__ cout)
{
    const int t    = blockIdx.x;
    const int tid  = threadIdx.x;
    const int w    = tid >> 6;
    const int lane = tid & 63;
    const int idx  = (w << 7) + lane;

    const float x = xs[0];
    const float b_i = bih[t]         + bhh[t]         + x * Wih0[t];
    const float b_f = bih[H + t]     + bhh[H + t]     + x * Wih0[H + t];
    const float b_g = bih[2 * H + t] + bhh[2 * H + t] + x * Wih0[2 * H + t];
    const float b_o = bih[3 * H + t] + bhh[3 * H + t] + x * Wih0[3 * H + t];
    const float cprev = cin[t];

    const float4* h4 = (const float4*)hin;
    const float4* wi = (const float4*)(Whh + (size_t)t * H);
    const float4* wf = (const float4*)(Whh + (size_t)(H + t) * H);
    const float4* wg = (const float4*)(Whh + (size_t)(2 * H + t) * H);
    const float4* wo = (const float4*)(Whh + (size_t)(3 * H + t) * H);

    const float4 hv0 = h4[idx], hv1 = h4[idx + 64];
    float4 a0 = wi[idx], a1 = wi[idx + 64];
    float4 b0 = wf[idx], b1 = wf[idx + 64];
    float4 c0 = wg[idx], c1 = wg[idx + 64];
    float4 d0 = wo[idx], d1 = wo[idx + 64];
    __builtin_amdgcn_sched_barrier(0);

    float s_i = dot4(a0, hv0) + dot4(a1, hv1);
    float s_f = dot4(b0, hv0) + dot4(b1, hv1);
    float s_g = dot4(c0, hv0) + dot4(c1, hv1);
    float s_o = dot4(d0, hv0) + dot4(d1, hv1);

    bfly4(s_i, s_f, s_g, s_o);

    __shared__ float part[4][4];
    if (lane == 0) {
        part[w][0] = s_i; part[w][1] = s_f; part[w][2] = s_g; part[w][3] = s_o;
    }
    __syncthreads();
    if (tid == 0) {
        float gi = part[0][0] + part[1][0] + part[2][0] + part[3][0] + b_i;
        float gf = part[0][1] + part[1][1] + part[2][1] + part[3][1] + b_f;
        float gg = part[0][2] + part[1][2] + part[2][2] + part[3][2] + b_g;
        float go = part[0][3] + part[1][3] + part[2][3] + part[3][3] + b_o;
        float c2 = sigmoidf_(gf) * cprev + sigmoidf_(gi) * tanhf(gg);
        float h2 = sigmoidf_(go) * tanhf(c2);
        cout[t] = c2;
        hout[t] = h2;
    }
}

// y = dot(Wout, h) + bout   (single block)
__global__ __launch_bounds__(256)
void out_proj(const float* __restrict__ Wout,
              const float* __restrict__ bout,
              const float* __restrict__ h,
              float* __restrict__ y)
{
    __shared__ float partl[4];
    const int tid = threadIdx.x;
    const float4* W4 = (const float4*)Wout;
    const float4* h4 = (const float4*)h;
    float acc = 0.0f;
#pragma unroll
    for (int k = 0; k < 2; ++k) {
        int i = tid + 256 * k;
        float4 a = W4[i];
        float4 b = h4[i];
        acc += a.x * b.x + a.y * b.y + a.z * b.z + a.w * b.w;
    }
#pragma unroll
    for (int off = 32; off > 0; off >>= 1) acc += __shfl_down(acc, off, 64);
    if ((tid & 63) == 0) partl[tid >> 6] = acc;
    __syncthreads();
    if (tid == 0) y[0] = partl[0] + partl[1] + partl[2] + partl[3] + bout[0];
}

extern "C" void kernel_launch(void* const* d_in, const int* in_sizes, int n_in,
                              void* d_out, int out_size, void* d_ws, size_t ws_size,
                              hipStream_t stream) {
    const float* x    = (const float*)d_in[0];
    const float* hin  = (const float*)d_in[1];   // [3,1,H]
    const float* cin  = (const float*)d_in[2];   // [3,1,H]
    const float* Wih0 = (const float*)d_in[3];
    const float* Whh0 = (const float*)d_in[4];
    const float* bih0 = (const float*)d_in[5];
    const float* bhh0 = (const float*)d_in[6];
    const float* Wih1 = (const float*)d_in[7];
    const float* Whh1 = (const float*)d_in[8];
    const float* bih1 = (const float*)d_in[9];
    const float* bhh1 = (const float*)d_in[10];
    const float* Wih2 = (const float*)d_in[11];
    const float* Whh2 = (const float*)d_in[12];
    const float* bih2 = (const float*)d_in[13];
    const float* bhh2 = (const float*)d_in[14];
    const float* Wout = (const float*)d_in[15];
    const float* bout = (const float*)d_in[16];

    float* out = (float*)d_out;
    float* y  = out;              // [1]
    float* hN = out + 1;          // [3,H]
    float* cN = out + 1 + 3 * H;  // [3,H]

    lstm_layer0<<<2048, 256, 0, stream>>>(Wih0, Whh0, bih0, bhh0, x,
                                          hin, cin, hN, cN);
    lstm_layer<<<2048, 256, 0, stream>>>(Wih1, Whh1, bih1, bhh1,
                                         hN, hin + H, cin + H,
                                         hN + H, cN + H);
    lstm_layer<<<2048, 256, 0, stream>>>(Wih2, Whh2, bih2, bhh2,
                                         hN + H, hin + 2 * H, cin + 2 * H,
                                         hN + 2 * H, cN + 2 * H);
    out_proj<<<1, 256, 0, stream>>>(Wout, bout, hN + 2 * H, y);
}